// Round 5
// baseline (40.048 us; speedup 1.0000x reference)
//
#include <hip/hip_runtime.h>
#include <stdint.h>
#include <math.h>

typedef uint32_t u32;
typedef uint64_t u64;

#define BB 8
#define CAT 10
#define HW 262144             // 512*512
#define WW 512
#define KSEL 500
#define CHUNKS 16             // prefilter WGs per plane
#define CH (HW / CHUNKS)      // 16384 elems per chunk
#define NCH (CAT * CHUNKS)    // 160 chunk-regions per batch
#define LCAP 32               // per-chunk candidate capacity (mean 6.8, sigma 2.6 -> ~10 sigma)
#define CANDCAP 2048          // per-batch candidate capacity (mean 1049, sigma 32)
#define SLICES 16             // k_rank WGs per batch; SLICES*128 == CANDCAP
#define THRV 0.9996f
#define NB 4096               // fallback histogram buckets

// order-preserving float->u32 (ascending)
__device__ __forceinline__ u32 f2u(float f) {
    u32 b = __float_as_uint(f);
    return (b & 0x80000000u) ? ~b : (b | 0x80000000u);
}
__device__ __forceinline__ float u2f(u32 u) {
    u32 b = (u & 0x80000000u) ? (u ^ 0x80000000u) : ~u;
    return __uint_as_float(b);
}
__device__ __forceinline__ int bucketOf(float v) {   // exact monotone (pow2 scale)
    int b = (int)floorf(v * (float)NB);
    return min(max(b, 0), NB - 1);
}
// combined key: score desc, then (class asc, idx asc); combo < 10*2^18 <= 0x3FFFFF
__device__ __forceinline__ u64 make_key(float v, int c, int idx) {
    u32 combo = ((u32)c << 18) | (u32)idx;
    return ((u64)f2u(v) << 32) | (u32)(0x3FFFFFu - combo);
}

// ---------------- Kernel A: streaming prefilter, direct scatter to private regions ----
__global__ __launch_bounds__(256) void k_prefilter(const float* __restrict__ heat,
                                                   u32* __restrict__ cnts,
                                                   u64* __restrict__ prebuf) {
    const int bc = blockIdx.y;       // 0..79
    const int chunk = blockIdx.x;    // 0..CHUNKS-1
    const int tid = threadIdx.x;
    const int c = bc % CAT;
    __shared__ u32 lcnt;
    if (tid == 0) lcnt = 0;
    __syncthreads();

    const float4* hp = (const float4*)(heat + (size_t)bc * HW + (size_t)chunk * CH);
    const int base_idx = chunk * CH;
    u64* pb = prebuf + ((size_t)bc * CHUNKS + chunk) * LCAP;

#pragma unroll 8
    for (int it = 0; it < CH / (256 * 4); ++it) {   // 16 iters, 8 float4 loads in flight
        int i4 = it * 256 + tid;
        float4 v = hp[i4];
        int e0 = base_idx + i4 * 4;
        float vv[4] = {v.x, v.y, v.z, v.w};
#pragma unroll
        for (int j = 0; j < 4; ++j) {
            if (vv[j] > THRV) {
                u32 pos = atomicAdd(&lcnt, 1u);
                if (pos < LCAP) pb[pos] = make_key(vv[j], c, e0 + j);   // rare: ~7/chunk
            }
        }
    }
    __syncthreads();
    if (tid == 0) cnts[bc * CHUNKS + chunk] = lcnt;   // plain store; no memset needed
}

// ---- fallback helpers (512 threads) ----
__device__ __forceinline__ int find_b1_512(u32* h, u32* ps0, u32* ps1, int* b1_s) {
    const int tid = threadIdx.x;
    u32 p = 0;
#pragma unroll
    for (int q = 0; q < 8; ++q) p += h[tid * 8 + q];
    ps0[tid] = p;
    __syncthreads();
    u32* src = ps0;
    u32* dst = ps1;
    for (int off = 1; off < 512; off <<= 1) {        // suffix scan
        u32 v = src[tid] + ((tid + off < 512) ? src[tid + off] : 0);
        dst[tid] = v;
        __syncthreads();
        u32* t = src; src = dst; dst = t;
    }
    u32 S_t = src[tid];
    u32 S_next = (tid < 511) ? src[tid + 1] : 0;
    if (S_t >= KSEL && (tid == 511 || S_next < KSEL)) {
        u32 run = (tid == 511) ? 0u : S_next;
        int b1 = tid * 8;
        for (int q = 7; q >= 0; --q) {
            run += h[tid * 8 + q];
            if (run >= KSEL) { b1 = tid * 8 + q; break; }
        }
        *b1_s = b1;
    }
    __syncthreads();
    return *b1_s;
}

__device__ __forceinline__ void bitonic_sort_desc_512(u64* cand) {
    const int tid = threadIdx.x;
    for (int k2 = 2; k2 <= CANDCAP; k2 <<= 1) {
        for (int j = k2 >> 1; j > 0; j >>= 1) {
            for (int i = tid; i < CANDCAP; i += 512) {
                int ixj = i ^ j;
                if (ixj > i) {
                    u64 a = cand[i], b = cand[ixj];
                    bool up = ((i & k2) == 0);
                    if ((a < b) == up) { cand[i] = b; cand[ixj] = a; }
                }
            }
            __syncthreads();
        }
    }
}

// decode + write one winner at output slot `rank` of batch b
__device__ __forceinline__ void decode_write(int b, int rank, float score, int cls, int ridx,
                                             const float* __restrict__ rot_sine,
                                             const float* __restrict__ rot_cosine,
                                             const float* __restrict__ hei,
                                             const float* __restrict__ dim,
                                             const float* __restrict__ vel,
                                             const float* __restrict__ reg,
                                             float* __restrict__ out) {
    float xs = (float)(ridx % WW);
    float ys = (float)(ridx / WW);
    size_t base = (size_t)b * HW;
    float r0 = reg[((size_t)(b * 2 + 0)) * HW + ridx];
    float r1 = reg[((size_t)(b * 2 + 1)) * HW + ridx];
    float rs = rot_sine[base + ridx];
    float rc = rot_cosine[base + ridx];
    float hg = hei[base + ridx];
    float d0 = dim[((size_t)(b * 3 + 0)) * HW + ridx];
    float d1 = dim[((size_t)(b * 3 + 1)) * HW + ridx];
    float d2 = dim[((size_t)(b * 3 + 2)) * HW + ridx];
    float v0 = vel[((size_t)(b * 2 + 0)) * HW + ridx];
    float v1 = vel[((size_t)(b * 2 + 1)) * HW + ridx];

    float x = (xs + r0) * 0.8f + (-51.2f);
    float y = (ys + r1) * 0.8f + (-51.2f);
    float rot = atan2f(rs, rc);

    size_t obase = ((size_t)b * KSEL + rank) * 9;
    out[obase + 0] = x;
    out[obase + 1] = y;
    out[obase + 2] = hg;
    out[obase + 3] = d0;
    out[obase + 4] = d1;
    out[obase + 5] = d2;
    out[obase + 6] = rot;
    out[obase + 7] = v0;
    out[obase + 8] = v1;

    const int NOUT = BB * KSEL;              // 4000
    out[9 * NOUT + b * KSEL + rank] = score;
    out[10 * NOUT + b * KSEL + rank] = (float)cls;
    bool keep = (x >= -61.2f) && (y >= -61.2f) && (hg >= -10.0f) &&
                (x <= 61.2f) && (y <= 61.2f) && (hg <= 10.0f) &&
                (score > 0.1f);
    out[11 * NOUT + b * KSEL + rank] = keep ? 1.0f : 0.0f;
}

// ---------------- Kernel B: rank-count top-k + decode; exact fallback inside ----
__global__ __launch_bounds__(512) void k_rank(const float* __restrict__ heat,
                                              const u32* __restrict__ cnts,
                                              const u64* __restrict__ prebuf,
                                              const float* __restrict__ rot_sine,
                                              const float* __restrict__ rot_cosine,
                                              const float* __restrict__ hei,
                                              const float* __restrict__ dim,
                                              const float* __restrict__ vel,
                                              const float* __restrict__ reg,
                                              float* __restrict__ out) {
    const int b = blockIdx.y;
    const int slice = blockIdx.x;
    const int tid = threadIdx.x;
    const int lane = tid & 63;
    const int wave = tid >> 6;

    __shared__ __align__(16) char smem[76928];          // manually overlaid
    // fast-path layout
    u64* keys = (u64*)smem;                             // [2048] 16 KB
    u32* cc   = (u32*)(smem + 16384);                   // [160]
    u32* sc0  = (u32*)(smem + 17024);                   // [256]
    u32* sc1  = (u32*)(smem + 18048);                   // [256]  -> ends 19072
    // fallback overlay (cc/sc dead once fb decided)
    u32* h    = (u32*)smem;                             // [4096] 16 KB
    u64* cand = (u64*)(smem + 16384);                   // [2048] 16 KB
    u32* ps0  = (u32*)(smem + 32768);                   // [512]
    u32* ps1  = (u32*)(smem + 34816);                   // [512]
    u64* s1k  = (u64*)(smem + 36864);                   // [5000] 40 KB -> ends 76864
    __shared__ int fb_s;
    __shared__ int b1_s;
    __shared__ int cnt_s;

    if (tid == 0) fb_s = 0;
    __syncthreads();
    const u32* cb = cnts + b * NCH;
    if (tid < NCH) {
        u32 v = cb[tid];
        cc[tid] = v;
        if (v > LCAP) fb_s = 1;                         // same-value race OK
    }
    if (tid < 256) sc0[tid] = (tid < NCH) ? ((tid < NCH) ? 0 : 0) : 0;  // placeholder init
    __syncthreads();
    if (tid < 256) sc0[tid] = (tid < NCH) ? cc[tid] : 0;
    __syncthreads();
    // Hillis-Steele inclusive scan over 256 entries
    u32* src = sc0; u32* dst = sc1;
    for (int off = 1; off < 256; off <<= 1) {
        if (tid < 256) dst[tid] = src[tid] + ((tid >= off) ? src[tid - off] : 0);
        __syncthreads();
        u32* t = src; src = dst; dst = t;
    }
    u32 tot = src[NCH - 1];
    if (tid == 0 && (tot < KSEL || tot > CANDCAP)) fb_s = 1;
    __syncthreads();
    int fb = fb_s;

    if (!fb) {
        // ---- fast path: coalesced wave-cooperative gather into LDS ----
        const u64* pbb = prebuf + (size_t)b * NCH * LCAP;
        for (int t = 0; t < NCH / 16; ++t) {            // 10 iters, 2 regions per wave
            int r = t * 16 + wave * 2 + (lane >> 5);
            u32 n = cc[r];
            u32 off = src[r] - n;                       // exclusive offset
            int l = lane & 31;
            if ((u32)l < n) keys[off + l] = pbb[(size_t)r * LCAP + l];
        }
        __syncthreads();

        // rank-count: 4 threads per candidate, shuffle-reduce
        int ci = slice * 128 + (tid >> 2);
        int sub = tid & 3;
        if (ci < (int)tot) {
            u64 mk = keys[ci];
            u32 q = (tot + 3) >> 2;
            u32 j0 = (u32)sub * q;
            u32 j1 = min(j0 + q, tot);
            u32 r = 0;
#pragma unroll 4
            for (u32 j = j0; j < j1; ++j) r += (keys[j] > mk);   // LDS broadcast reads
            r += __shfl_xor(r, 1);
            r += __shfl_xor(r, 2);
            if (sub == 0 && r < KSEL) {
                float score = u2f((u32)(mk >> 32));
                u32 combo = 0x3FFFFFu - (u32)(mk & 0xFFFFFFFFull);
                int cls = (int)(combo >> 18);
                int ridx = (int)(combo & 0x3FFFFu);
                decode_write(b, (int)r, score, cls, ridx,
                             rot_sine, rot_cosine, hei, dim, vel, reg, out);
            }
        }
        return;
    }

    // ---- exact fallback (not taken for this data; correctness safety net) ----
    if (slice != 0) return;
    for (int c = 0; c < CAT; ++c) {
        const float* hp = heat + (size_t)(b * CAT + c) * HW;
        for (int i = tid; i < NB; i += 512) h[i] = 0;
        if (tid == 0) cnt_s = 0;
        __syncthreads();
        for (int i = tid; i < HW; i += 512) atomicAdd(&h[bucketOf(hp[i])], 1u);
        __syncthreads();
        int b1 = find_b1_512(h, ps0, ps1, &b1_s);
        for (int i = tid; i < HW; i += 512) {
            float v = hp[i];
            if (bucketOf(v) >= b1) {
                int pos = atomicAdd(&cnt_s, 1);
                if (pos < CANDCAP)
                    cand[pos] = ((u64)f2u(v) << 32) | (u32)(~(u32)i);
            }
        }
        __syncthreads();
        int c2 = min(cnt_s, CANDCAP);
        for (int i = c2 + tid; i < CANDCAP; i += 512) cand[i] = 0;
        __syncthreads();
        bitonic_sort_desc_512(cand);
        for (int r2 = tid; r2 < KSEL; r2 += 512) s1k[c * KSEL + r2] = cand[r2];
        __syncthreads();
    }
    // stage 2 over s1k[5000], tie-break by flat position
    const int NCAND = CAT * KSEL;
    for (int i = tid; i < NB; i += 512) h[i] = 0;
    if (tid == 0) cnt_s = 0;
    __syncthreads();
    for (int i = tid; i < NCAND; i += 512)
        atomicAdd(&h[bucketOf(u2f((u32)(s1k[i] >> 32)))], 1u);
    __syncthreads();
    int b1 = find_b1_512(h, ps0, ps1, &b1_s);
    for (int i = tid; i < NCAND; i += 512) {
        u64 k1 = s1k[i];
        float v = u2f((u32)(k1 >> 32));
        if (bucketOf(v) >= b1) {
            int pos = atomicAdd(&cnt_s, 1);
            if (pos < CANDCAP)
                cand[pos] = (k1 & 0xFFFFFFFF00000000ull) | (u32)(~(u32)i);
        }
    }
    __syncthreads();
    int c2 = min(cnt_s, CANDCAP);
    for (int i = c2 + tid; i < CANDCAP; i += 512) cand[i] = 0;
    __syncthreads();
    bitonic_sort_desc_512(cand);
    for (int r2 = tid; r2 < KSEL; r2 += 512) {
        u64 kk = cand[r2];
        float score = u2f((u32)(kk >> 32));
        int flat = (int)(~(u32)kk);
        int cls = flat / KSEL;
        int ridx = (int)(~(u32)s1k[flat]);
        decode_write(b, r2, score, cls, ridx,
                     rot_sine, rot_cosine, hei, dim, vel, reg, out);
    }
}

extern "C" void kernel_launch(void* const* d_in, const int* in_sizes, int n_in,
                              void* d_out, int out_size, void* d_ws, size_t ws_size,
                              hipStream_t stream) {
    const float* heat       = (const float*)d_in[0];
    const float* rot_sine   = (const float*)d_in[1];
    const float* rot_cosine = (const float*)d_in[2];
    const float* hei        = (const float*)d_in[3];
    const float* dim        = (const float*)d_in[4];
    const float* vel        = (const float*)d_in[5];
    const float* reg        = (const float*)d_in[6];

    char* ws = (char*)d_ws;
    // layout: cnts 80*16*4 = 5120 B | pad to 8192 | prebuf 80*16*32*8 = 327680 B
    u32* cnts   = (u32*)ws;
    u64* prebuf = (u64*)(ws + 8192);
    // no memset needed: every cnts slot is written unconditionally by k_prefilter

    k_prefilter<<<dim3(CHUNKS, BB * CAT), 256, 0, stream>>>(heat, cnts, prebuf);
    k_rank<<<dim3(SLICES, BB), 512, 0, stream>>>(heat, cnts, prebuf,
                                                 rot_sine, rot_cosine, hei, dim, vel, reg,
                                                 (float*)d_out);
}